// Round 1
// 2276.521 us; speedup vs baseline: 5.7822x; 5.7822x over previous
//
#include <hip/hip_runtime.h>
#include <stdint.h>

#define B_ 32
#define T_ 512
#define E_ 256
#define U_ 512
#define N3U_ 1536

typedef __bf16 bf16_t;
typedef bf16_t bf16x8 __attribute__((ext_vector_type(8)));
typedef float f32x4 __attribute__((ext_vector_type(4)));

__device__ __forceinline__ unsigned short f2bf(float x) {
    union { float f; unsigned int u; } v; v.f = x;
    return (unsigned short)((v.u + 0x7fffu + ((v.u >> 16) & 1u)) >> 16);
}
__device__ __forceinline__ float bf2f(unsigned short h) {
    union { unsigned int u; float f; } v; v.u = ((unsigned int)h) << 16;
    return v.f;
}

// ---------- Kernel 1: xp[dir] = bf16( bf16(emb[tokens]) @ bf16(W) + b_in ) ----------
// grid (24, 256, 2), block 256. 64x64 tile, K=256 in two 128-halves. bf16 out to ws.
// (GEMM structure correctness proven end-to-end by R5 PASS.)
__global__ __launch_bounds__(256) void gemm_xproj(
    const int* __restrict__ tokens, const float* __restrict__ emb,
    const float* __restrict__ Wf, const float* __restrict__ Wb,
    const float* __restrict__ binf, const float* __restrict__ binb,
    unsigned short* __restrict__ xpf, unsigned short* __restrict__ xpb)
{
    const int dir = blockIdx.z;
    const float* W   = dir ? Wb   : Wf;
    const float* bin = dir ? binb : binf;
    unsigned short* xp = dir ? xpb : xpf;

    const int n0 = blockIdx.x << 6;
    const int m0 = blockIdx.y << 6;
    const int tid  = threadIdx.x;
    const int lane = tid & 63;
    const int w    = tid >> 6;

    __shared__ __align__(16) unsigned short Ash[64][136];
    __shared__ __align__(16) unsigned short Bsh[64][136];

    f32x4 acc[4];
    for (int f = 0; f < 4; ++f) acc[f] = (f32x4){0.f, 0.f, 0.f, 0.f};

    for (int kt = 0; kt < 2; ++kt) {
        const int kbase = kt << 7;
        for (int p = 0; p < 8; ++p) {
            int row = (p << 3) + (tid >> 5);
            int c   = tid & 31;
            int tok = tokens[m0 + row];
            float4 v = *(const float4*)&emb[tok * E_ + kbase + (c << 2)];
            ushort4 o;
            o.x = f2bf(v.x); o.y = f2bf(v.y); o.z = f2bf(v.z); o.w = f2bf(v.w);
            *(ushort4*)&Ash[row][c << 2] = o;
        }
        for (int p = 0; p < 8; ++p) {
            int kl = (p << 4) + (tid >> 4);
            int j4 = (tid & 15) << 2;
            float4 v = *(const float4*)&W[(kbase + kl) * N3U_ + n0 + j4];
            Bsh[j4 + 0][kl] = f2bf(v.x);
            Bsh[j4 + 1][kl] = f2bf(v.y);
            Bsh[j4 + 2][kl] = f2bf(v.z);
            Bsh[j4 + 3][kl] = f2bf(v.w);
        }
        __syncthreads();
        for (int ks = 0; ks < 4; ++ks) {
            int off = (ks << 5) + ((lane >> 4) << 3);
            bf16x8 a = *(const bf16x8*)&Ash[(w << 4) + (lane & 15)][off];
            for (int f = 0; f < 4; ++f) {
                bf16x8 b = *(const bf16x8*)&Bsh[(f << 4) + (lane & 15)][off];
                acc[f] = __builtin_amdgcn_mfma_f32_16x16x32_bf16(a, b, acc[f], 0, 0, 0);
            }
        }
        __syncthreads();
    }
    // C/D layout: col(N)=lane&15, row(M)=(lane>>4)*4+reg
    const int col_l = lane & 15;
    const int mrow  = (w << 4) + ((lane >> 4) << 2);
    for (int f = 0; f < 4; ++f) {
        int col = n0 + (f << 4) + col_l;
        float bb = bin[col];
        for (int r = 0; r < 4; ++r) {
            int m = m0 + mrow + r;
            xp[m * N3U_ + col] = f2bf(acc[f][r] + bb);
        }
    }
}

// ---------- Kernel 2: bidirectional masked GRU scan, weight-stationary MFMA ----------
// 128 blocks: dir(2) x batch-group mg(2) x u-slice us(32).  256 threads (4 waves).
// Block holds its 16-u x 3-gate slice of U as register B-fragments for all 512 steps.
//
// R6 change (fence elimination): h state is packed (lo<<16|hi) in ONE u32 array and
// ALL cross-block h traffic uses relaxed AGENT-scope atomics (sc0 sc1: L1/L2-bypass,
// write-through to the coherent IF$). This removes the per-step __threadfence() pair,
// which on gfx950 compiled to buffer_wbl2 sc1 + buffer_inv sc1 = full local-L2
// writeback + invalidate per block per step (the 26 us/step latency, per rocprof:
// all pipes <1% busy). Release ordering for the barrier = s_waitcnt vmcnt(0) on all
// threads + __syncthreads before tid0's atomicAdd; acquire side needs nothing since
// the h loads themselves bypass the (possibly stale) local caches.
__global__ __launch_bounds__(256) void gru_scan(
    const unsigned short* __restrict__ xpf, const unsigned short* __restrict__ xpb,
    const float* __restrict__ Uf, const float* __restrict__ Ub,
    const float* __restrict__ brf, const float* __restrict__ brb,
    const int* __restrict__ tokens,
    unsigned int* __restrict__ hpk,
    unsigned int* __restrict__ ctr,
    float* __restrict__ out)
{
    const int bx  = blockIdx.x;
    const int us  = bx & 31;
    const int mg  = (bx >> 5) & 1;
    const int dir = bx >> 6;
    const int u0  = us << 4;
    const int tid  = threadIdx.x;
    const int lane = tid & 63;
    const int w    = tid >> 6;
    const int group = (dir << 1) | mg;

    const unsigned short* xp = dir ? xpb : xpf;
    const float* Uw = dir ? Ub : Uf;
    const float* br = dir ? brb : brf;

    __shared__ __align__(16) unsigned short Ahi[16][520];
    __shared__ __align__(16) unsigned short Alo[16][520];
    __shared__ __align__(16) float red[3072];   // [3 gates][4 waves][16 b][16 u]

    // stationary weight fragments: wave w covers k in [w*128, w*128+128)
    bf16x8 wfrag[4][3];
    {
        const int quad = lane >> 4, nl = lane & 15;
        for (int ks = 0; ks < 4; ++ks)
            for (int g = 0; g < 3; ++g) {
                union { bf16x8 v; unsigned short s[8]; } uu;
                for (int j = 0; j < 8; ++j) {
                    int k   = (w << 7) + (ks << 5) + (quad << 3) + j;
                    int col = (g << 9) + u0 + nl;
                    uu.s[j] = f2bf(Uw[k * N3U_ + col]);
                }
                wfrag[ks][g] = uu.v;
            }
    }

    const int bl = tid >> 4;           // local batch row 0..15
    const int ul = tid & 15;           // local u 0..15
    const int bg = (mg << 4) + bl;     // global batch
    const int ug = u0 + ul;            // global u
    float hreg = 0.f;
    const float brz = br[ug], brr = br[512 + ug], brh = br[1024 + ug];

    for (int s = 0; s < T_; ++s) {
        const int t    = dir ? (T_ - 1 - s) : s;
        const int bufr = s & 1, bufw = bufr ^ 1;

        // early independent loads (used in epilogue); normal cached loads —
        // producer is the previous kernel, kernel-boundary flush covers them.
        const int xrow = (bg * T_ + t) * N3U_;
        const unsigned short xzu = xp[xrow + ug];
        const unsigned short xru = xp[xrow + 512 + ug];
        const unsigned short xhu = xp[xrow + 1024 + ug];
        const int tok = tokens[bg * T_ + t];

        // stage this mg's 16 rows of packed h: 16 independent 8B sc1 loads
        // batched into registers (one exposed IF$ latency), then unpack to LDS.
        const int hbase = (((bufr << 1) + dir) << 14) + (mg << 13);
        unsigned long long hv[16];
#pragma unroll
        for (int q = 0; q < 16; ++q)
            hv[q] = __hip_atomic_load(
                (const unsigned long long*)&hpk[hbase + (q << 9) + (tid << 1)],
                __ATOMIC_RELAXED, __HIP_MEMORY_SCOPE_AGENT);
        const int cc = tid << 1;
#pragma unroll
        for (int q = 0; q < 16; ++q) {
            unsigned int w0 = (unsigned int)hv[q];
            unsigned int w1 = (unsigned int)(hv[q] >> 32);
            *(unsigned int*)&Ahi[q][cc] = (w0 & 0xffffu) | (w1 << 16);
            *(unsigned int*)&Alo[q][cc] = (w0 >> 16) | (w1 & 0xffff0000u);
        }
        __syncthreads();

        f32x4 acc[3];
        acc[0] = (f32x4){0.f,0.f,0.f,0.f};
        acc[1] = (f32x4){0.f,0.f,0.f,0.f};
        acc[2] = (f32x4){0.f,0.f,0.f,0.f};
        for (int ks = 0; ks < 4; ++ks) {
            int off = (w << 7) + (ks << 5) + ((lane >> 4) << 3);
            bf16x8 ahi = *(const bf16x8*)&Ahi[lane & 15][off];
            bf16x8 alo = *(const bf16x8*)&Alo[lane & 15][off];
            for (int g = 0; g < 3; ++g) {
                acc[g] = __builtin_amdgcn_mfma_f32_16x16x32_bf16(ahi, wfrag[ks][g], acc[g], 0, 0, 0);
                acc[g] = __builtin_amdgcn_mfma_f32_16x16x32_bf16(alo, wfrag[ks][g], acc[g], 0, 0, 0);
            }
        }
        // cross-wave (k-split) reduction via LDS
        for (int g = 0; g < 3; ++g)
            for (int r = 0; r < 4; ++r)
                red[(((g << 2) + w) << 8) + ((((lane >> 4) << 2) + r) << 4) + (lane & 15)] = acc[g][r];
        __syncthreads();

        float rz = brz, rr = brr, rh = brh;
        for (int ww = 0; ww < 4; ++ww) {
            rz += red[((0 + ww) << 8) + (bl << 4) + ul];
            rr += red[((4 + ww) << 8) + (bl << 4) + ul];
            rh += red[((8 + ww) << 8) + (bl << 4) + ul];
        }
        float xz = bf2f(xzu), xr = bf2f(xru), xh = bf2f(xhu);
        float z    = 1.f / (1.f + expf(-(xz + rz)));
        float rg   = 1.f / (1.f + expf(-(xr + rr)));
        float cand = tanhf(xh + rg * rh);
        float hn   = z * hreg + (1.f - z) * cand;
        float ho   = (tok != 0) ? hn : hreg;   // Keras masking: carry state
        hreg = ho;

        out[(bg * T_ + t) * 1024 + (dir << 9) + ug] = ho;   // f32 output

        // write-through h (hi in low16, lo in high16) — visible at IF$, no fence
        unsigned short hi = f2bf(ho);
        unsigned short lo = f2bf(ho - bf2f(hi));
        int hw = (((bufw << 1) + dir) << 14) + (bg << 9) + ug;
        __hip_atomic_store(&hpk[hw], ((unsigned int)lo << 16) | (unsigned int)hi,
                           __ATOMIC_RELAXED, __HIP_MEMORY_SCOPE_AGENT);

        // release: every thread drains its own sc1 store, then block-barrier,
        // then tid0 publishes arrival. No cache writeback/invalidate ops.
        asm volatile("s_waitcnt vmcnt(0)" ::: "memory");
        __syncthreads();
        if (tid == 0) {
            atomicAdd(&ctr[group << 4], 1u);
            const unsigned int target = (unsigned int)(s + 1) << 5;
            while (__hip_atomic_load(&ctr[group << 4], __ATOMIC_RELAXED, __HIP_MEMORY_SCOPE_AGENT) < target)
                __builtin_amdgcn_s_sleep(2);
        }
        __syncthreads();
    }
}

extern "C" void kernel_launch(void* const* d_in, const int* in_sizes, int n_in,
                              void* d_out, int out_size, void* d_ws, size_t ws_size,
                              hipStream_t stream)
{
    const size_t XP_BYTES  = (size_t)B_ * T_ * N3U_ * 2;    // 50,331,648 per dir (bf16)
    const size_t H_OFF     = 2 * XP_BYTES;                  // 100,663,296
    const size_t HPK_BYTES = (size_t)2 * 2 * 32 * 512 * 4;  // 262,144 (2 bufs x 2 dirs, packed u32)
    const size_t CTR_OFF   = H_OFF + HPK_BYTES;             // 100,925,440
    const size_t NEED      = CTR_OFF + 256;                 // 4 counters padded to 64B lines
    if (ws_size < NEED) return;  // fail visibly

    const int*   tokens = (const int*)d_in[0];
    const float* emb    = (const float*)d_in[1];
    const float* W_fw   = (const float*)d_in[2];
    const float* U_fw   = (const float*)d_in[3];
    const float* bin_fw = (const float*)d_in[4];
    const float* brc_fw = (const float*)d_in[5];
    const float* W_bw   = (const float*)d_in[6];
    const float* U_bw   = (const float*)d_in[7];
    const float* bin_bw = (const float*)d_in[8];
    const float* brc_bw = (const float*)d_in[9];

    char* ws = (char*)d_ws;
    unsigned short* xpf = (unsigned short*)ws;
    unsigned short* xpb = (unsigned short*)(ws + XP_BYTES);
    unsigned int*   hpk = (unsigned int*)(ws + H_OFF);
    unsigned int*   ctr = (unsigned int*)(ws + CTR_OFF);
    float* outp = (float*)d_out;

    // zero h state (both buffers) + barrier counters, every call
    hipMemsetAsync(ws + H_OFF, 0, HPK_BYTES + 256, stream);

    gemm_xproj<<<dim3(24, 256, 2), dim3(256), 0, stream>>>(
        tokens, emb, W_fw, W_bw, bin_fw, bin_bw, xpf, xpb);

    void* args[] = { (void*)&xpf, (void*)&xpb, (void*)&U_fw, (void*)&U_bw,
                     (void*)&brc_fw, (void*)&brc_bw, (void*)&tokens,
                     (void*)&hpk, (void*)&ctr, (void*)&outp };
    hipLaunchCooperativeKernel((const void*)gru_scan, dim3(128), dim3(256), args, 0, stream);
}